// Round 5
// baseline (191.077 us; speedup 1.0000x reference)
//
#include <hip/hip_runtime.h>
#include <hip/hip_bf16.h>

#define NH 6
#define DIM 192
#define HW 192
#define M_TOK (HW*HW)
// SCALE*log2e and log2e
#define QSC 0.25503488f
#define L2E 1.4426950408889634f

typedef __attribute__((ext_vector_type(8))) __bf16 bf16x8;
typedef __attribute__((ext_vector_type(8))) short short8;
typedef __attribute__((ext_vector_type(4))) short s16x4;
typedef __attribute__((ext_vector_type(4))) float floatx4;

__device__ inline unsigned short f2bf(float f) {
    union { float f; unsigned int u; } v; v.f = f;
    unsigned int r = (v.u + 0x7FFFu + ((v.u >> 16) & 1u)) >> 16;
    return (unsigned short)r;
}
__device__ inline short f2bfh(float f) {
    __bf16 b = (__bf16)f;
    return __builtin_bit_cast(short, b);
}
__device__ inline float exp2fast(float x) {
#if __has_builtin(__builtin_amdgcn_exp2f)
    return __builtin_amdgcn_exp2f(x);
#else
    return exp2f(x);
#endif
}

__device__ inline floatx4 mfma16(short8 a, short8 b, floatx4 c) {
    return __builtin_amdgcn_mfma_f32_16x16x32_bf16(
        __builtin_bit_cast(bf16x8, a), __builtin_bit_cast(bf16x8, b), c, 0, 0, 0);
}

// K=16 MFMA: D(16x16) = A(16x16) * B(16x16) + C, 4 bf16/lane operands
__device__ inline floatx4 mfma16k16(s16x4 a, s16x4 b, floatx4 c) {
#if __has_builtin(__builtin_amdgcn_mfma_f32_16x16x16bf16_1k)
    return __builtin_amdgcn_mfma_f32_16x16x16bf16_1k(a, b, c, 0, 0, 0);
#else
    floatx4 d;
    asm volatile("v_mfma_f32_16x16x16_bf16 %0, %1, %2, %3"
                 : "=v"(d) : "v"(a), "v"(b), "v"(c));
    return d;
#endif
}

template <int OFF>
__device__ inline s16x4 tr16(unsigned addr) {
    s16x4 r;
    asm volatile("ds_read_b64_tr_b16 %0, %1 offset:%2"
                 : "=&v"(r) : "v"(addr), "i"(OFF));
    return r;
}
template <int N>
__device__ __forceinline__ void wait_lgkm() {
    asm volatile("s_waitcnt lgkmcnt(%0)" :: "i"(N) : "memory");
}

// async global->LDS, 16B per lane; lds_off = wave-uniform LDS byte offset
__device__ __forceinline__ void gload16(const void* g, unsigned lds_off) {
    __builtin_amdgcn_global_load_lds(
        (const __attribute__((address_space(1))) unsigned int*)(uintptr_t)g,
        (__attribute__((address_space(3))) unsigned int*)(uintptr_t)lds_off,
        16, 0, 0);
}

// ---- cast + transpose weight: w (K x N) f32 -> wt (N x K) bf16 ----
__global__ void wcast_kernel(const float* __restrict__ w, unsigned short* __restrict__ wt,
                             int K, int N) {
    int id = blockIdx.x * 256 + threadIdx.x;
    if (id >= K * N) return;
    int n = id / K, k = id - n * K;
    wt[id] = f2bf(w[k * N + n]);
}

// ---- expand rel-pos bias into S^T MFMA D-fragment order, pre-multiplied by log2e ----
// btf[(((hh*16+qt)*36+ktg)*64+lane)*4 + r] =
//   bias[q = qt*16 + (lane&15)][k = ktg*16 + 4*(lane>>4) + r] * L2E
__global__ void btfrag_kernel(const int* __restrict__ rpi, const float* __restrict__ table,
                              float* __restrict__ btf) {
    int id = blockIdx.x * 256 + threadIdx.x;   // 221184 total
    if (id >= 221184) return;
    int lane = id & 63;
    int t = id >> 6;
    int ktg = t % 36; t /= 36;
    int qt = t & 15; int hh = t >> 4;
    int q = qt * 16 + (lane & 15);
    int kb = ktg * 16 + (lane >> 4) * 4;
    floatx4 v;
    #pragma unroll
    for (int r = 0; r < 4; r++)
        v[r] = table[rpi[q * 576 + kb + r] * NH + hh] * L2E;
    *(floatx4*)&btf[(size_t)id * 4] = v;
}

// ---- LayerNorm: f32 in -> bf16 out, one wave per row of 192 ----
__global__ __launch_bounds__(256) void ln_kernel(const float* __restrict__ in,
                                                 const float* __restrict__ g,
                                                 const float* __restrict__ b,
                                                 unsigned short* __restrict__ out) {
    int row = blockIdx.x * 4 + (threadIdx.x >> 6);
    int lane = threadIdx.x & 63;
    const float* r = in + (size_t)row * DIM;
    float x0 = r[lane], x1 = r[lane + 64], x2 = r[lane + 128];
    float s = x0 + x1 + x2;
    #pragma unroll
    for (int m = 32; m >= 1; m >>= 1) s += __shfl_xor(s, m);
    float mean = s * (1.f / 192.f);
    float d0 = x0 - mean, d1 = x1 - mean, d2 = x2 - mean;
    float v = d0 * d0 + d1 * d1 + d2 * d2;
    #pragma unroll
    for (int m = 32; m >= 1; m >>= 1) v += __shfl_xor(v, m);
    float rstd = rsqrtf(v * (1.f / 192.f) + 1e-5f);
    unsigned short* o = out + (size_t)row * DIM;
    o[lane]       = f2bf(d0 * rstd * g[lane]       + b[lane]);
    o[lane + 64]  = f2bf(d1 * rstd * g[lane + 64]  + b[lane + 64]);
    o[lane + 128] = f2bf(d2 * rstd * g[lane + 128] + b[lane + 128]);
}

// ---- bf16 MFMA GEMM, global_load_lds staging, 96-col K-slabs ----
template <int MODE, int KK>
__global__ __launch_bounds__(256, 4) void gemm_kernel(
    const unsigned short* __restrict__ A,
    const unsigned short* __restrict__ Wt,
    const float* __restrict__ bias,
    const float* __restrict__ res,
    void* __restrict__ outp,
    int N) {
    __shared__ __align__(16) short sAB[19968];   // A: 13312 shorts, B at 13312
    constexpr int STAGES = KK / 96;
    int tid = threadIdx.x;
    int w = tid >> 6, lane = tid & 63;
    int bm = blockIdx.x, bn = blockIdx.y;
    int lr = lane & 15, h = lane >> 4;
    floatx4 acc[2][4];
    #pragma unroll
    for (int i = 0; i < 2; i++)
        #pragma unroll
        for (int j = 0; j < 4; j++) acc[i][j] = (floatx4){0.f, 0.f, 0.f, 0.f};

    unsigned ldsbase = (unsigned)(uintptr_t)&sAB[0];

    for (int s = 0; s < STAGES; s++) {
        if (s) __syncthreads();
        for (int W = w; W < 39; W += 4) {
            int o = W * 1024 + lane * 16;
            const unsigned short* src;
            if (o < 26624) {                       // A region (wave-uniform branch)
                int r = o / 208;
                int c = (o - r * 208) >> 4; c = c < 12 ? c : 11;
                src = &A[(size_t)(bm * 128 + r) * KK + s * 96 + c * 8];
            } else {
                int o2 = o - 26624;
                int r = o2 / 208;
                int c = (o2 - r * 208) >> 4; c = c < 12 ? c : 11;
                src = &Wt[(size_t)(bn * 64 + r) * KK + s * 96 + c * 8];
            }
            gload16(src, ldsbase + (unsigned)(W * 1024));
        }
        __syncthreads();
        #pragma unroll
        for (int kk = 0; kk < 3; kk++) {
            int kc = (kk * 4 + h) * 8;
            short8 a0 = *(const short8*)&sAB[(w * 32 + lr) * 104 + kc];
            short8 a1 = *(const short8*)&sAB[(w * 32 + 16 + lr) * 104 + kc];
            short8 b0 = *(const short8*)&sAB[13312 + (lr) * 104 + kc];
            short8 b1 = *(const short8*)&sAB[13312 + (16 + lr) * 104 + kc];
            short8 b2 = *(const short8*)&sAB[13312 + (32 + lr) * 104 + kc];
            short8 b3 = *(const short8*)&sAB[13312 + (48 + lr) * 104 + kc];
            acc[0][0] = mfma16(a0, b0, acc[0][0]);
            acc[0][1] = mfma16(a0, b1, acc[0][1]);
            acc[0][2] = mfma16(a0, b2, acc[0][2]);
            acc[0][3] = mfma16(a0, b3, acc[0][3]);
            acc[1][0] = mfma16(a1, b0, acc[1][0]);
            acc[1][1] = mfma16(a1, b1, acc[1][1]);
            acc[1][2] = mfma16(a1, b2, acc[1][2]);
            acc[1][3] = mfma16(a1, b3, acc[1][3]);
        }
    }

    int rowbase = bm * 128 + w * 32 + h * 4;
    int colbase = bn * 64;
    #pragma unroll
    for (int mi = 0; mi < 2; mi++) {
        #pragma unroll
        for (int ni = 0; ni < 4; ni++) {
            int c = colbase + ni * 16 + lr;
            float bv = bias[c];
            #pragma unroll
            for (int j = 0; j < 4; j++) {
                int r = rowbase + mi * 16 + j;
                size_t idx = (size_t)r * N + c;
                float v = acc[mi][ni][j] + bv;
                if (MODE == 0) {
                    if (c < 192) v *= QSC;
                    ((unsigned short*)outp)[idx] = f2bf(v);
                } else if (MODE == 1) {
                    ((float*)outp)[idx] = v + res[idx];
                } else if (MODE == 2) {
                    float gl = 0.5f * v * (1.f + erff(v * 0.70710678118654752f));
                    ((unsigned short*)outp)[idx] = f2bf(gl);
                } else {
                    ((float*)outp)[idx] = v + ((float*)outp)[idx];
                }
            }
        }
    }
}

// ---- MFMA windowed attention, swapped-QK^T / in-register-P edition ----
// Block = (window, head), 4 waves; wave w owns q-tiles i = w*4..w*4+3.
// S^T = mfma(A=K, B=Q): lane(m,h) gets S^T[key=16kt+4h+r][q=m] -> after exp,
// each lane holds P[q=m][keys 16kt+4h+r] = EXACTLY the A-frag of a K=16 MFMA.
// PV: 16x16x16 MFMAs, V via tr-reads (window 2048*dt + 512*kt + 128*h + 8*m).
// No P LDS traffic at all; row-sums via VALU + 2 shuffles.
__global__ __launch_bounds__(256, 4) void attn_mfma_kernel(
    const unsigned short* __restrict__ qkv,
    const float* __restrict__ btf,
    unsigned short* __restrict__ out) {
    __shared__ __align__(16) short sK[2][2304];
    __shared__ __align__(16) short sV[2][2048];
    int win = blockIdx.x, head = blockIdx.y;
    int iy = win / 12, ix = win % 12;
    int tid = threadIdx.x;
    int w = tid >> 6, lane = tid & 63;
    int m = lane & 15, h = lane >> 4;

    // Q fragments (pre-scaled by SCALE*log2e in the qkv GEMM epilogue)
    short8 qf[4];
    #pragma unroll
    for (int i = 0; i < 4; i++) {
        int wy = w * 4 + i;
        size_t tok = (size_t)(iy * 16 + wy) * HW + ix * 16 + m;
        qf[i] = *(const short8*)&qkv[tok * 576 + head * 32 + h * 8];
    }

    floatx4 oacc[4][2];
    float li[4];
    #pragma unroll
    for (int i = 0; i < 4; i++) {
        li[i] = 0.f;
        oacc[i][0] = (floatx4){0.f, 0.f, 0.f, 0.f};
        oacc[i][1] = (floatx4){0.f, 0.f, 0.f, 0.f};
    }

    int skey = tid >> 2, dq = tid & 3;
    short* kdst = &sK[0][skey * 36 + dq * 8];
    short* vdst = &sV[0][(dq >> 1) * 1024 + (skey >> 2) * 64 + (skey & 3) * 16 + (dq & 1) * 8];

    auto fetch = [&](int c, short8& kv, short8& vv) {
        int key = c * 64 + skey;
        int oy = key / 24, ox = key - (key / 24) * 24;
        int gy = iy * 16 - 4 + oy, gx = ix * 16 - 4 + ox;
        kv = (short8){0,0,0,0,0,0,0,0};
        vv = (short8){0,0,0,0,0,0,0,0};
        if (gy >= 0 && gy < HW && gx >= 0 && gx < HW) {
            const unsigned short* p = &qkv[((size_t)gy * HW + gx) * 576 + 192 + head * 32 + dq * 8];
            kv = *(const short8*)p;
            vv = *(const short8*)(p + 192);
        }
    };

    {   // stage chunk 0 into buffer 0
        short8 kv, vv;
        fetch(0, kv, vv);
        *(short8*)kdst = kv;
        *(short8*)vdst = vv;
    }

    unsigned sVa0 = (unsigned)(uintptr_t)&sV[0][0] + 128 * h + 8 * m;

    for (int c = 0; c < 9; c++) {
        __syncthreads();
        int cur = c & 1;
        short8 knx, vnx;
        bool more = (c < 8);
        if (more) fetch(c + 1, knx, vnx);   // global loads in flight during compute

        const short* sKc = sK[cur];
        short8 kfrag[4];
        #pragma unroll
        for (int kt = 0; kt < 4; kt++)
            kfrag[kt] = *(const short8*)&sKc[(kt * 16 + m) * 36 + h * 8];

        // V B-frags (K=16 shape) via tr reads: vbb[kt][dt] = V[key=16kt+4h+j][d=16dt+m]
        unsigned sVa = sVa0 + cur * 4096;
        s16x4 vbb[4][2];
        vbb[0][0] = tr16<0>(sVa);    vbb[0][1] = tr16<2048>(sVa);
        vbb[1][0] = tr16<512>(sVa);  vbb[1][1] = tr16<2560>(sVa);
        vbb[2][0] = tr16<1024>(sVa); vbb[2][1] = tr16<3072>(sVa);
        vbb[3][0] = tr16<1536>(sVa); vbb[3][1] = tr16<3584>(sVa);
        wait_lgkm<0>();
        __builtin_amdgcn_sched_barrier(0);

        const float* bb = btf + ((((size_t)head * 16 + w * 4) * 36 + c * 4) * 64 + lane) * 4;

        #pragma unroll
        for (int i = 0; i < 4; i++) {
            floatx4 s[4];
            #pragma unroll
            for (int kt = 0; kt < 4; kt++)
                s[kt] = *(const floatx4*)&bb[(size_t)(i * 36 + kt) * 256];
            #pragma unroll
            for (int kt = 0; kt < 4; kt++)
                s[kt] = mfma16(kfrag[kt], qf[i], s[kt]);   // S^T = K·Q

            // P = exp2(S^T): in-register, already in K=16 A-frag layout
            s16x4 p[4];
            float lsum = 0.f;
            #pragma unroll
            for (int kt = 0; kt < 4; kt++) {
                #pragma unroll
                for (int r = 0; r < 4; r++) {
                    float e = exp2fast(s[kt][r]);
                    lsum += e;
                    p[kt][r] = f2bfh(e);
                }
            }
            li[i] += lsum;

            #pragma unroll
            for (int kt = 0; kt < 4; kt++) {
                oacc[i][0] = mfma16k16(p[kt], vbb[kt][0], oacc[i][0]);
                oacc[i][1] = mfma16k16(p[kt], vbb[kt][1], oacc[i][1]);
            }
        }

        if (more) {   // write prefetched chunk into the other buffer
            int nb = 1 - cur;
            *(short8*)(kdst + nb * 2304) = knx;
            *(short8*)(vdst + nb * 2048) = vnx;
        }
    }

    // ---- cross-h-group row-sum reduce, normalize + store ----
    #pragma unroll
    for (int i = 0; i < 4; i++) {
        li[i] += __shfl_xor(li[i], 16);
        li[i] += __shfl_xor(li[i], 32);
    }
    #pragma unroll
    for (int i = 0; i < 4; i++) {
        float inv[4];
        #pragma unroll
        for (int r = 0; r < 4; r++)
            inv[r] = 1.f / __shfl(li[i], 4 * h + r);
        int wy = w * 4 + i;
        #pragma unroll
        for (int dt = 0; dt < 2; dt++)
            #pragma unroll
            for (int r = 0; r < 4; r++) {
                size_t tok = (size_t)(iy * 16 + wy) * HW + ix * 16 + h * 4 + r;
                out[tok * DIM + head * 32 + dt * 16 + m] = f2bf(oacc[i][dt][r] * inv[r]);
            }
    }
}

extern "C" void kernel_launch(void* const* d_in, const int* in_sizes, int n_in,
                              void* d_out, int out_size, void* d_ws, size_t ws_size,
                              hipStream_t stream) {
    const float* x     = (const float*)d_in[0];
    const int*   rpi   = (const int*)d_in[1];
    const float* n1g   = (const float*)d_in[4];
    const float* n1b   = (const float*)d_in[5];
    const float* qkvw  = (const float*)d_in[6];
    const float* qkvb  = (const float*)d_in[7];
    const float* rpb   = (const float*)d_in[8];
    const float* projw = (const float*)d_in[9];
    const float* projb = (const float*)d_in[10];
    const float* n2g   = (const float*)d_in[11];
    const float* n2b   = (const float*)d_in[12];
    const float* fc1w  = (const float*)d_in[13];
    const float* fc1b  = (const float*)d_in[14];
    const float* fc2w  = (const float*)d_in[15];
    const float* fc2b  = (const float*)d_in[16];

    char* ws = (char*)d_ws;
    unsigned short* wt_qkv  = (unsigned short*)ws;          // 110592 elems
    unsigned short* wt_proj = wt_qkv + 110592;              // 36864
    unsigned short* wt_fc1  = wt_proj + 36864;              // 73728
    unsigned short* wt_fc2  = wt_fc1 + 73728;               // 73728
    float*          btf     = (float*)(ws + 589824);        // 884736 f32 (frag-order bias)
    unsigned short* xn      = (unsigned short*)(ws + 4128768);   // 36864*192 bf16
    unsigned short* qkv     = (unsigned short*)(ws + 18284544);  // 36864*576 bf16
    unsigned short* attn_o  = (unsigned short*)(ws + 60751872);  // 36864*192 bf16
    float* outf = (float*)d_out;

    wcast_kernel<<<(110592 + 255) / 256, 256, 0, stream>>>(qkvw, wt_qkv, 192, 576);
    wcast_kernel<<<(36864 + 255) / 256, 256, 0, stream>>>(projw, wt_proj, 192, 192);
    wcast_kernel<<<(73728 + 255) / 256, 256, 0, stream>>>(fc1w, wt_fc1, 192, 384);
    wcast_kernel<<<(73728 + 255) / 256, 256, 0, stream>>>(fc2w, wt_fc2, 384, 192);
    btfrag_kernel<<<(221184 + 255) / 256, 256, 0, stream>>>(rpi, rpb, btf);
    ln_kernel<<<M_TOK / 4, 256, 0, stream>>>(x, n1g, n1b, xn);
    gemm_kernel<0, 192><<<dim3(288, 9), 256, 0, stream>>>(
        xn, wt_qkv, qkvb, nullptr, qkv, 576);
    attn_mfma_kernel<<<dim3(144, 6), 256, 0, stream>>>(qkv, btf, attn_o);
    gemm_kernel<1, 192><<<dim3(288, 3), 256, 0, stream>>>(
        attn_o, wt_proj, projb, x, d_out, 192);
    ln_kernel<<<M_TOK / 4, 256, 0, stream>>>(outf, n2g, n2b, xn);
    gemm_kernel<2, 192><<<dim3(288, 6), 256, 0, stream>>>(
        xn, wt_fc1, fc1b, nullptr, qkv, 384);
    gemm_kernel<3, 384><<<dim3(288, 3), 256, 0, stream>>>(
        qkv, wt_fc2, fc2b, nullptr, d_out, 192);
}

// Round 6
// 184.919 us; speedup vs baseline: 1.0333x; 1.0333x over previous
//
#include <hip/hip_runtime.h>
#include <hip/hip_bf16.h>

#define NH 6
#define DIM 192
#define HW 192
#define M_TOK (HW*HW)
// SCALE*log2e and log2e
#define QSC 0.25503488f
#define L2E 1.4426950408889634f

typedef __attribute__((ext_vector_type(8))) __bf16 bf16x8;
typedef __attribute__((ext_vector_type(8))) short short8;
typedef __attribute__((ext_vector_type(4))) short s16x4;
typedef __attribute__((ext_vector_type(4))) float floatx4;

__device__ inline unsigned short f2bf(float f) {
    union { float f; unsigned int u; } v; v.f = f;
    unsigned int r = (v.u + 0x7FFFu + ((v.u >> 16) & 1u)) >> 16;
    return (unsigned short)r;
}
__device__ inline short f2bfh(float f) {
    __bf16 b = (__bf16)f;
    return __builtin_bit_cast(short, b);
}
__device__ inline float exp2fast(float x) {
#if __has_builtin(__builtin_amdgcn_exp2f)
    return __builtin_amdgcn_exp2f(x);
#else
    return exp2f(x);
#endif
}
// bf16x4 -> f32x4 (bit shift)
__device__ inline floatx4 bf4f(s16x4 b) {
    floatx4 f;
    #pragma unroll
    for (int r = 0; r < 4; r++) {
        union { unsigned u; float f; } v;
        v.u = ((unsigned)(unsigned short)b[r]) << 16;
        f[r] = v.f;
    }
    return f;
}

__device__ inline floatx4 mfma16(short8 a, short8 b, floatx4 c) {
    return __builtin_amdgcn_mfma_f32_16x16x32_bf16(
        __builtin_bit_cast(bf16x8, a), __builtin_bit_cast(bf16x8, b), c, 0, 0, 0);
}

// K=16 MFMA: D(16x16) = A(16x16) * B(16x16) + C, 4 bf16/lane operands
__device__ inline floatx4 mfma16k16(s16x4 a, s16x4 b, floatx4 c) {
#if __has_builtin(__builtin_amdgcn_mfma_f32_16x16x16bf16_1k)
    return __builtin_amdgcn_mfma_f32_16x16x16bf16_1k(a, b, c, 0, 0, 0);
#else
    floatx4 d;
    asm volatile("v_mfma_f32_16x16x16_bf16 %0, %1, %2, %3"
                 : "=v"(d) : "v"(a), "v"(b), "v"(c));
    return d;
#endif
}

template <int OFF>
__device__ inline s16x4 tr16(unsigned addr) {
    s16x4 r;
    asm volatile("ds_read_b64_tr_b16 %0, %1 offset:%2"
                 : "=&v"(r) : "v"(addr), "i"(OFF));
    return r;
}
template <int N>
__device__ __forceinline__ void wait_lgkm() {
    asm volatile("s_waitcnt lgkmcnt(%0)" :: "i"(N) : "memory");
}

// async global->LDS, 16B per lane; lds_off = wave-uniform LDS byte offset
__device__ __forceinline__ void gload16(const void* g, unsigned lds_off) {
    __builtin_amdgcn_global_load_lds(
        (const __attribute__((address_space(1))) unsigned int*)(uintptr_t)g,
        (__attribute__((address_space(3))) unsigned int*)(uintptr_t)lds_off,
        16, 0, 0);
}

// ---- cast + transpose weight: w (K x N) f32 -> wt (N x K) bf16 ----
__global__ void wcast_kernel(const float* __restrict__ w, unsigned short* __restrict__ wt,
                             int K, int N) {
    int id = blockIdx.x * 256 + threadIdx.x;
    if (id >= K * N) return;
    int n = id / K, k = id - n * K;
    wt[id] = f2bf(w[k * N + n]);
}

// ---- expand rel-pos bias into S^T MFMA D-fragment order, bf16, pre-*log2e ----
// btf[(((hh*16+qt)*36+ktg)*64+lane)*4 + r] =
//   bf16( bias[q = qt*16 + (lane&15)][k = ktg*16 + 4*(lane>>4) + r] * L2E )
__global__ void btfrag_kernel(const int* __restrict__ rpi, const float* __restrict__ table,
                              unsigned short* __restrict__ btf) {
    int id = blockIdx.x * 256 + threadIdx.x;   // 221184 total
    if (id >= 221184) return;
    int lane = id & 63;
    int t = id >> 6;
    int ktg = t % 36; t /= 36;
    int qt = t & 15; int hh = t >> 4;
    int q = qt * 16 + (lane & 15);
    int kb = ktg * 16 + (lane >> 4) * 4;
    s16x4 v;
    #pragma unroll
    for (int r = 0; r < 4; r++)
        v[r] = f2bfh(table[rpi[q * 576 + kb + r] * NH + hh] * L2E);
    *(s16x4*)&btf[(size_t)id * 4] = v;
}

// ---- LayerNorm: f32 in -> bf16 out, one wave per row of 192 ----
__global__ __launch_bounds__(256) void ln_kernel(const float* __restrict__ in,
                                                 const float* __restrict__ g,
                                                 const float* __restrict__ b,
                                                 unsigned short* __restrict__ out) {
    int row = blockIdx.x * 4 + (threadIdx.x >> 6);
    int lane = threadIdx.x & 63;
    const float* r = in + (size_t)row * DIM;
    float x0 = r[lane], x1 = r[lane + 64], x2 = r[lane + 128];
    float s = x0 + x1 + x2;
    #pragma unroll
    for (int m = 32; m >= 1; m >>= 1) s += __shfl_xor(s, m);
    float mean = s * (1.f / 192.f);
    float d0 = x0 - mean, d1 = x1 - mean, d2 = x2 - mean;
    float v = d0 * d0 + d1 * d1 + d2 * d2;
    #pragma unroll
    for (int m = 32; m >= 1; m >>= 1) v += __shfl_xor(v, m);
    float rstd = rsqrtf(v * (1.f / 192.f) + 1e-5f);
    unsigned short* o = out + (size_t)row * DIM;
    o[lane]       = f2bf(d0 * rstd * g[lane]       + b[lane]);
    o[lane + 64]  = f2bf(d1 * rstd * g[lane + 64]  + b[lane + 64]);
    o[lane + 128] = f2bf(d2 * rstd * g[lane + 128] + b[lane + 128]);
}

// ---- bf16 MFMA GEMM, global_load_lds staging, 96-col K-slabs ----
template <int MODE, int KK>
__global__ __launch_bounds__(256, 4) void gemm_kernel(
    const unsigned short* __restrict__ A,
    const unsigned short* __restrict__ Wt,
    const float* __restrict__ bias,
    const float* __restrict__ res,
    void* __restrict__ outp,
    int N) {
    __shared__ __align__(16) short sAB[19968];   // A: 13312 shorts, B at 13312
    constexpr int STAGES = KK / 96;
    int tid = threadIdx.x;
    int w = tid >> 6, lane = tid & 63;
    int bm = blockIdx.x, bn = blockIdx.y;
    int lr = lane & 15, h = lane >> 4;
    floatx4 acc[2][4];
    #pragma unroll
    for (int i = 0; i < 2; i++)
        #pragma unroll
        for (int j = 0; j < 4; j++) acc[i][j] = (floatx4){0.f, 0.f, 0.f, 0.f};

    unsigned ldsbase = (unsigned)(uintptr_t)&sAB[0];

    for (int s = 0; s < STAGES; s++) {
        if (s) __syncthreads();
        for (int W = w; W < 39; W += 4) {
            int o = W * 1024 + lane * 16;
            const unsigned short* src;
            if (o < 26624) {                       // A region (wave-uniform branch)
                int r = o / 208;
                int c = (o - r * 208) >> 4; c = c < 12 ? c : 11;
                src = &A[(size_t)(bm * 128 + r) * KK + s * 96 + c * 8];
            } else {
                int o2 = o - 26624;
                int r = o2 / 208;
                int c = (o2 - r * 208) >> 4; c = c < 12 ? c : 11;
                src = &Wt[(size_t)(bn * 64 + r) * KK + s * 96 + c * 8];
            }
            gload16(src, ldsbase + (unsigned)(W * 1024));
        }
        __syncthreads();
        #pragma unroll
        for (int kk = 0; kk < 3; kk++) {
            int kc = (kk * 4 + h) * 8;
            short8 a0 = *(const short8*)&sAB[(w * 32 + lr) * 104 + kc];
            short8 a1 = *(const short8*)&sAB[(w * 32 + 16 + lr) * 104 + kc];
            short8 b0 = *(const short8*)&sAB[13312 + (lr) * 104 + kc];
            short8 b1 = *(const short8*)&sAB[13312 + (16 + lr) * 104 + kc];
            short8 b2 = *(const short8*)&sAB[13312 + (32 + lr) * 104 + kc];
            short8 b3 = *(const short8*)&sAB[13312 + (48 + lr) * 104 + kc];
            acc[0][0] = mfma16(a0, b0, acc[0][0]);
            acc[0][1] = mfma16(a0, b1, acc[0][1]);
            acc[0][2] = mfma16(a0, b2, acc[0][2]);
            acc[0][3] = mfma16(a0, b3, acc[0][3]);
            acc[1][0] = mfma16(a1, b0, acc[1][0]);
            acc[1][1] = mfma16(a1, b1, acc[1][1]);
            acc[1][2] = mfma16(a1, b2, acc[1][2]);
            acc[1][3] = mfma16(a1, b3, acc[1][3]);
        }
    }

    int rowbase = bm * 128 + w * 32 + h * 4;
    int colbase = bn * 64;
    #pragma unroll
    for (int mi = 0; mi < 2; mi++) {
        #pragma unroll
        for (int ni = 0; ni < 4; ni++) {
            int c = colbase + ni * 16 + lr;
            float bv = bias[c];
            #pragma unroll
            for (int j = 0; j < 4; j++) {
                int r = rowbase + mi * 16 + j;
                size_t idx = (size_t)r * N + c;
                float v = acc[mi][ni][j] + bv;
                if (MODE == 0) {
                    if (c < 192) v *= QSC;
                    ((unsigned short*)outp)[idx] = f2bf(v);
                } else if (MODE == 1) {
                    ((float*)outp)[idx] = v + res[idx];
                } else if (MODE == 2) {
                    float gl = 0.5f * v * (1.f + erff(v * 0.70710678118654752f));
                    ((unsigned short*)outp)[idx] = f2bf(gl);
                } else {
                    ((float*)outp)[idx] = v + ((float*)outp)[idx];
                }
            }
        }
    }
}

// ---- MFMA windowed attention, swapped-QK^T / in-register-P edition ----
// 1D grid of 864 with head-contiguous XCD swizzle: g = (bid&7)*108 + (bid>>3);
// head = g/144 (<=2 heads per XCD -> bias stays L2-resident), win = g%144
// (raster-contiguous windows share K/V halos in L2).
__global__ __launch_bounds__(256, 4) void attn_mfma_kernel(
    const unsigned short* __restrict__ qkv,
    const unsigned short* __restrict__ btf,
    unsigned short* __restrict__ out) {
    __shared__ __align__(16) short sK[2][2304];
    __shared__ __align__(16) short sV[2][2048];
    int bid = blockIdx.x;
    int g = (bid & 7) * 108 + (bid >> 3);
    int head = g / 144;
    int win = g - head * 144;
    int iy = win / 12, ix = win % 12;
    int tid = threadIdx.x;
    int w = tid >> 6, lane = tid & 63;
    int m = lane & 15, h = lane >> 4;

    // Q fragments (pre-scaled by SCALE*log2e in the qkv GEMM epilogue)
    short8 qf[4];
    #pragma unroll
    for (int i = 0; i < 4; i++) {
        int wy = w * 4 + i;
        size_t tok = (size_t)(iy * 16 + wy) * HW + ix * 16 + m;
        qf[i] = *(const short8*)&qkv[tok * 576 + head * 32 + h * 8];
    }

    floatx4 oacc[4][2];
    float li[4];
    #pragma unroll
    for (int i = 0; i < 4; i++) {
        li[i] = 0.f;
        oacc[i][0] = (floatx4){0.f, 0.f, 0.f, 0.f};
        oacc[i][1] = (floatx4){0.f, 0.f, 0.f, 0.f};
    }

    int skey = tid >> 2, dq = tid & 3;
    short* kdst = &sK[0][skey * 36 + dq * 8];
    short* vdst = &sV[0][(dq >> 1) * 1024 + (skey >> 2) * 64 + (skey & 3) * 16 + (dq & 1) * 8];

    auto fetch = [&](int c, short8& kv, short8& vv) {
        int key = c * 64 + skey;
        int oy = key / 24, ox = key - (key / 24) * 24;
        int gy = iy * 16 - 4 + oy, gx = ix * 16 - 4 + ox;
        kv = (short8){0,0,0,0,0,0,0,0};
        vv = (short8){0,0,0,0,0,0,0,0};
        if (gy >= 0 && gy < HW && gx >= 0 && gx < HW) {
            const unsigned short* p = &qkv[((size_t)gy * HW + gx) * 576 + 192 + head * 32 + dq * 8];
            kv = *(const short8*)p;
            vv = *(const short8*)(p + 192);
        }
    };

    {   // stage chunk 0 into buffer 0
        short8 kv, vv;
        fetch(0, kv, vv);
        *(short8*)kdst = kv;
        *(short8*)vdst = vv;
    }

    unsigned sVa0 = (unsigned)(uintptr_t)&sV[0][0] + 128 * h + 8 * m;

    for (int c = 0; c < 9; c++) {
        __syncthreads();
        int cur = c & 1;
        short8 knx, vnx;
        bool more = (c < 8);
        if (more) fetch(c + 1, knx, vnx);   // global loads in flight during compute

        const short* sKc = sK[cur];
        short8 kfrag[4];
        #pragma unroll
        for (int kt = 0; kt < 4; kt++)
            kfrag[kt] = *(const short8*)&sKc[(kt * 16 + m) * 36 + h * 8];

        // V B-frags (K=16 shape) via tr reads: vbb[kt][dt] = V[key=16kt+4h+j][d=16dt+m]
        unsigned sVa = sVa0 + cur * 4096;
        s16x4 vbb[4][2];
        vbb[0][0] = tr16<0>(sVa);    vbb[0][1] = tr16<2048>(sVa);
        vbb[1][0] = tr16<512>(sVa);  vbb[1][1] = tr16<2560>(sVa);
        vbb[2][0] = tr16<1024>(sVa); vbb[2][1] = tr16<3072>(sVa);
        vbb[3][0] = tr16<1536>(sVa); vbb[3][1] = tr16<3584>(sVa);
        wait_lgkm<0>();
        __builtin_amdgcn_sched_barrier(0);

        const unsigned short* bb = btf + ((((size_t)head * 16 + w * 4) * 36 + c * 4) * 64 + lane) * 4;

        #pragma unroll
        for (int i = 0; i < 4; i++) {
            floatx4 s[4];
            #pragma unroll
            for (int kt = 0; kt < 4; kt++)
                s[kt] = bf4f(*(const s16x4*)&bb[(size_t)(i * 36 + kt) * 256]);
            #pragma unroll
            for (int kt = 0; kt < 4; kt++)
                s[kt] = mfma16(kfrag[kt], qf[i], s[kt]);   // S^T = K·Q

            // P = exp2(S^T): in-register, already in K=16 A-frag layout
            s16x4 p[4];
            float lsum = 0.f;
            #pragma unroll
            for (int kt = 0; kt < 4; kt++) {
                #pragma unroll
                for (int r = 0; r < 4; r++) {
                    float e = exp2fast(s[kt][r]);
                    lsum += e;
                    p[kt][r] = f2bfh(e);
                }
            }
            li[i] += lsum;

            #pragma unroll
            for (int kt = 0; kt < 4; kt++) {
                oacc[i][0] = mfma16k16(p[kt], vbb[kt][0], oacc[i][0]);
                oacc[i][1] = mfma16k16(p[kt], vbb[kt][1], oacc[i][1]);
            }
        }

        if (more) {   // write prefetched chunk into the other buffer
            int nb = 1 - cur;
            *(short8*)(kdst + nb * 2304) = knx;
            *(short8*)(vdst + nb * 2048) = vnx;
        }
    }

    // ---- cross-h-group row-sum reduce, normalize + store ----
    #pragma unroll
    for (int i = 0; i < 4; i++) {
        li[i] += __shfl_xor(li[i], 16);
        li[i] += __shfl_xor(li[i], 32);
    }
    #pragma unroll
    for (int i = 0; i < 4; i++) {
        float inv[4];
        #pragma unroll
        for (int r = 0; r < 4; r++)
            inv[r] = 1.f / __shfl(li[i], 4 * h + r);
        int wy = w * 4 + i;
        #pragma unroll
        for (int dt = 0; dt < 2; dt++)
            #pragma unroll
            for (int r = 0; r < 4; r++) {
                size_t tok = (size_t)(iy * 16 + wy) * HW + ix * 16 + h * 4 + r;
                out[tok * DIM + head * 32 + dt * 16 + m] = f2bf(oacc[i][dt][r] * inv[r]);
            }
    }
}

extern "C" void kernel_launch(void* const* d_in, const int* in_sizes, int n_in,
                              void* d_out, int out_size, void* d_ws, size_t ws_size,
                              hipStream_t stream) {
    const float* x     = (const float*)d_in[0];
    const int*   rpi   = (const int*)d_in[1];
    const float* n1g   = (const float*)d_in[4];
    const float* n1b   = (const float*)d_in[5];
    const float* qkvw  = (const float*)d_in[6];
    const float* qkvb  = (const float*)d_in[7];
    const float* rpb   = (const float*)d_in[8];
    const float* projw = (const float*)d_in[9];
    const float* projb = (const float*)d_in[10];
    const float* n2g   = (const float*)d_in[11];
    const float* n2b   = (const float*)d_in[12];
    const float* fc1w  = (const float*)d_in[13];
    const float* fc1b  = (const float*)d_in[14];
    const float* fc2w  = (const float*)d_in[15];
    const float* fc2b  = (const float*)d_in[16];

    char* ws = (char*)d_ws;
    unsigned short* wt_qkv  = (unsigned short*)ws;          // 110592 elems
    unsigned short* wt_proj = wt_qkv + 110592;              // 36864
    unsigned short* wt_fc1  = wt_proj + 36864;              // 73728
    unsigned short* wt_fc2  = wt_fc1 + 73728;               // 73728
    unsigned short* btf     = (unsigned short*)(ws + 589824);    // 884736 bf16 (frag-order bias)
    unsigned short* xn      = (unsigned short*)(ws + 4128768);   // 36864*192 bf16
    unsigned short* qkv     = (unsigned short*)(ws + 18284544);  // 36864*576 bf16
    unsigned short* attn_o  = (unsigned short*)(ws + 60751872);  // 36864*192 bf16
    float* outf = (float*)d_out;

    wcast_kernel<<<(110592 + 255) / 256, 256, 0, stream>>>(qkvw, wt_qkv, 192, 576);
    wcast_kernel<<<(36864 + 255) / 256, 256, 0, stream>>>(projw, wt_proj, 192, 192);
    wcast_kernel<<<(73728 + 255) / 256, 256, 0, stream>>>(fc1w, wt_fc1, 192, 384);
    wcast_kernel<<<(73728 + 255) / 256, 256, 0, stream>>>(fc2w, wt_fc2, 384, 192);
    btfrag_kernel<<<(221184 + 255) / 256, 256, 0, stream>>>(rpi, rpb, btf);
    ln_kernel<<<M_TOK / 4, 256, 0, stream>>>(x, n1g, n1b, xn);
    gemm_kernel<0, 192><<<dim3(288, 9), 256, 0, stream>>>(
        xn, wt_qkv, qkvb, nullptr, qkv, 576);
    attn_mfma_kernel<<<dim3(864), 256, 0, stream>>>(qkv, btf, attn_o);
    gemm_kernel<1, 192><<<dim3(288, 3), 256, 0, stream>>>(
        attn_o, wt_proj, projb, x, d_out, 192);
    ln_kernel<<<M_TOK / 4, 256, 0, stream>>>(outf, n2g, n2b, xn);
    gemm_kernel<2, 192><<<dim3(288, 6), 256, 0, stream>>>(
        xn, wt_fc1, fc1b, nullptr, qkv, 384);
    gemm_kernel<3, 384><<<dim3(288, 3), 256, 0, stream>>>(
        qkv, wt_fc2, fc2b, nullptr, d_out, 192);
}